// Round 2
// baseline (227.844 us; speedup 1.0000x reference)
//
#include <hip/hip_runtime.h>
#include <hip/hip_fp16.h>

#define S_LEN 8192
#define T_LEN 8192
#define D_DIM 256
#define QBLK 128
#define KVBLK 64
#define TSPLIT 8
#define TCHUNK (T_LEN / TSPLIT)   // 1024
#define NKV (TCHUNK / KVBLK)      // 16
#define NQT (S_LEN / QBLK)        // 64
#define TILE_BYTES 32768          // 64 rows x 256 f16 (or 256 d x 64 keys)

typedef _Float16 f16x8 __attribute__((ext_vector_type(8)));
typedef float f32x4 __attribute__((ext_vector_type(4)));

struct h4 { _Float16 h[4]; };  // 8 bytes

#define GLOAD_LDS16(g, l)                                              \
    __builtin_amdgcn_global_load_lds(                                  \
        (const __attribute__((address_space(1))) void*)(g),            \
        (__attribute__((address_space(3))) void*)(l), 16, 0, 0)

// ---------------- fp32 -> f16 convert (row-major, for Q) ----------------
__global__ __launch_bounds__(256) void cvt_kernel(const float* __restrict__ in,
                                                  _Float16* __restrict__ out, int n4) {
    int i = blockIdx.x * 256 + threadIdx.x;
    if (i < n4) {
        float4 v = ((const float4*)in)[i];
        h4 o;
        o.h[0] = (_Float16)v.x; o.h[1] = (_Float16)v.y;
        o.h[2] = (_Float16)v.z; o.h[3] = (_Float16)v.w;
        ((h4*)out)[i] = o;
    }
}

// ------- K fp32 row-major -> Kimg: per-64-row tile LDS image, swizzle baked in -------
// Kimg[t*32768 + r*512 + ((ck ^ (r&7))<<4)] = f16(K[t*64+r][ck*8 .. ck*8+7])
__global__ __launch_bounds__(256) void cvt_swz_kernel(const float* __restrict__ in,
                                                      _Float16* __restrict__ img,
                                                      int nchunks) {
    int id = blockIdx.x * 256 + threadIdx.x;
    if (id >= nchunks) return;
    int row = id >> 5, ck = id & 31;
    int t = row >> 6, r = row & 63;
    float4 a = *(const float4*)(in + (size_t)row * D_DIM + ck * 8);
    float4 b = *(const float4*)(in + (size_t)row * D_DIM + ck * 8 + 4);
    f16x8 o;
    o[0] = (_Float16)a.x; o[1] = (_Float16)a.y; o[2] = (_Float16)a.z; o[3] = (_Float16)a.w;
    o[4] = (_Float16)b.x; o[5] = (_Float16)b.y; o[6] = (_Float16)b.z; o[7] = (_Float16)b.w;
    *(f16x8*)((char*)img + (size_t)t * TILE_BYTES + r * 512 + ((ck ^ (r & 7)) << 4)) = o;
}

// ------- V [T][D] fp32 -> Vimg: per-64-key tile, [256 d][64 keys] f16, swizzled -------
// Vimg[t*32768 + d*128 + ((tc ^ (d&7))<<4)] = f16(V[t*64 + tc*8 + j][d]), j=0..7
__global__ __launch_bounds__(256) void vt_swz_kernel(const float* __restrict__ V,
                                                     _Float16* __restrict__ Vimg) {
    __shared__ float tile[64][65];
    const int tb = blockIdx.x * 64;  // key base; tile index = blockIdx.x
    const int db = blockIdx.y * 64;  // d base
#pragma unroll
    for (int i = 0; i < 4; ++i) {
        int idx = i * 256 + threadIdx.x;  // 1024 float4s = 64 keys x 16 float4
        int tr = idx >> 4, c4 = idx & 15;
        float4 v = *(const float4*)(V + (size_t)(tb + tr) * D_DIM + db + c4 * 4);
        tile[tr][c4 * 4 + 0] = v.x;
        tile[tr][c4 * 4 + 1] = v.y;
        tile[tr][c4 * 4 + 2] = v.z;
        tile[tr][c4 * 4 + 3] = v.w;
    }
    __syncthreads();
#pragma unroll
    for (int it = 0; it < 2; ++it) {
        int idx = it * 256 + threadIdx.x;  // 512 chunks = 64 d x 8 tc
        int dl = idx >> 3, tc = idx & 7;
        int d = db + dl;
        f16x8 o;
#pragma unroll
        for (int j = 0; j < 8; ++j) o[j] = (_Float16)tile[tc * 8 + j][dl];
        *(f16x8*)((char*)Vimg + (size_t)blockIdx.x * TILE_BYTES + d * 128 +
                  ((tc ^ (d & 7)) << 4)) = o;
    }
}

// ---------------- flash attention, one (qtile, split) per block ----------------
// 512 threads = 8 waves; wave owns 16 query rows. LDS 64KB:
//   sK  [64][256] f16, row stride 512B, chunk swizzle ck^(r&7)  (staged via global_load_lds)
//   sVt [256][64] f16, row stride 128B, chunk swizzle tc^(d&7)  (staged via global_load_lds)
//   sP  aliases first 16KB of sK (per-wave 2KB), valid only after post-QK barrier
__global__ __launch_bounds__(512, 4) void attn_kernel(
    const _Float16* __restrict__ Qh, const _Float16* __restrict__ Kimg,
    const _Float16* __restrict__ Vimg, _Float16* __restrict__ Opart,
    float* __restrict__ ml) {
    __shared__ __align__(16) char smem[65536];
    const int tid = threadIdx.x;
    const int wave = tid >> 6, lane = tid & 63;
    const int g = lane >> 4, c = lane & 15;
    const int qtile = blockIdx.x, split = blockIdx.y;
    const int tile0 = split * NKV;

    char* sK = smem;
    char* sVt = smem + 32768;
    char* sP = smem + wave * 2048;  // wave-private, after post-QK barrier

    // ---- Q fragments: direct global loads (once per block, L2-resident) ----
    f16x8 qf[8];
    {
        const int qr = qtile * QBLK + wave * 16 + c;
#pragma unroll
        for (int ks = 0; ks < 8; ++ks)
            qf[ks] = *(const f16x8*)(Qh + (size_t)qr * D_DIM + (ks * 4 + g) * 8);
    }

    f32x4 acc[16];
#pragma unroll
    for (int dt = 0; dt < 16; ++dt) acc[dt] = (f32x4){0.f, 0.f, 0.f, 0.f};
    float mrow[4] = {-1e30f, -1e30f, -1e30f, -1e30f};
    float lrow[4] = {0.f, 0.f, 0.f, 0.f};

    const int soff = wave * 1024;          // wave-uniform LDS offset per round
    const int goff = soff + lane * 16;     // per-lane global offset

    for (int kt = 0; kt < NKV; ++kt) {
        const char* Kt = (const char*)Kimg + (size_t)(tile0 + kt) * TILE_BYTES;
        const char* Vt = (const char*)Vimg + (size_t)(tile0 + kt) * TILE_BYTES;
#pragma unroll
        for (int i = 0; i < 4; ++i) {
            GLOAD_LDS16(Kt + i * 8192 + goff, sK + i * 8192 + soff);
            GLOAD_LDS16(Vt + i * 8192 + goff, sVt + i * 8192 + soff);
        }
        __syncthreads();

        // ---- QK^T: S[16 rows][64 keys] per wave ----
        f32x4 s[4];
#pragma unroll
        for (int ct = 0; ct < 4; ++ct) s[ct] = (f32x4){0.f, 0.f, 0.f, 0.f};
#pragma unroll
        for (int ks = 0; ks < 8; ++ks) {
#pragma unroll
            for (int ct = 0; ct < 4; ++ct) {
                int kr = ct * 16 + c;
                f16x8 kf = *(const f16x8*)(sK + kr * 512 + (((ks * 4 + g) ^ (kr & 7)) << 4));
                s[ct] = __builtin_amdgcn_mfma_f32_16x16x32_f16(qf[ks], kf, s[ct], 0, 0, 0);
            }
        }
        __syncthreads();  // all waves done reading sK before sP overwrites it

        // ---- online softmax (C-layout: row=g*4+r, col=ct*16+c) ----
#pragma unroll
        for (int r = 0; r < 4; ++r) {
            float v = fmaxf(fmaxf(s[0][r], s[1][r]), fmaxf(s[2][r], s[3][r]));
#pragma unroll
            for (int off = 1; off < 16; off <<= 1) v = fmaxf(v, __shfl_xor(v, off));
            float mn = fmaxf(mrow[r], v);
            float sc = __expf(mrow[r] - mn);
            mrow[r] = mn;
            float rs = 0.f;
#pragma unroll
            for (int ct = 0; ct < 4; ++ct) {
                float p = __expf(s[ct][r] - mn);
                s[ct][r] = p;
                rs += p;
            }
#pragma unroll
            for (int off = 1; off < 16; off <<= 1) rs += __shfl_xor(rs, off);
            lrow[r] = lrow[r] * sc + rs;
#pragma unroll
            for (int dt = 0; dt < 16; ++dt) acc[dt][r] *= sc;
        }

        // ---- P (f32, C-layout) -> sP (f16, A-layout source), wave-private ----
#pragma unroll
        for (int ct = 0; ct < 4; ++ct)
#pragma unroll
            for (int r = 0; r < 4; ++r) {
                int row = g * 4 + r, col = ct * 16 + c;
                *(((_Float16*)(sP + row * 128 + (((col >> 3) ^ (row & 7)) << 4))) +
                  (col & 7)) = (_Float16)s[ct][r];
            }

        // ---- PV: acc[16 dtiles] += P[16][64] * V[64][256] ----
        f16x8 pf[2];
#pragma unroll
        for (int k2 = 0; k2 < 2; ++k2)
            pf[k2] = *(const f16x8*)(sP + c * 128 + (((k2 * 4 + g) ^ (c & 7)) << 4));
#pragma unroll
        for (int dt = 0; dt < 16; ++dt) {
#pragma unroll
            for (int k2 = 0; k2 < 2; ++k2) {
                int vr = dt * 16 + c;
                f16x8 vf = *(const f16x8*)(sVt + vr * 128 + (((k2 * 4 + g) ^ (vr & 7)) << 4));
                acc[dt] = __builtin_amdgcn_mfma_f32_16x16x32_f16(pf[k2], vf, acc[dt], 0, 0, 0);
            }
        }
        __syncthreads();  // PV + sP reads done before next tile staging
    }

    // ---- epilogue: unnormalized partial O (f16) + (m,l) ----
    _Float16* Ob = Opart + (size_t)(qtile * TSPLIT + split) * QBLK * D_DIM;
#pragma unroll
    for (int dt = 0; dt < 16; ++dt)
#pragma unroll
        for (int r = 0; r < 4; ++r) {
            int row = wave * 16 + g * 4 + r, col = dt * 16 + c;
            Ob[row * D_DIM + col] = (_Float16)acc[dt][r];
        }
    if (c == 0) {
        float* mlb = ml + (size_t)((qtile * TSPLIT + split) * QBLK) * 2;
#pragma unroll
        for (int r = 0; r < 4; ++r) {
            int row = wave * 16 + g * 4 + r;
            mlb[row * 2 + 0] = mrow[r];
            mlb[row * 2 + 1] = lrow[r];
        }
    }
}

// ---------------- combine TSPLIT partials ----------------
__global__ __launch_bounds__(256) void combine_kernel(const _Float16* __restrict__ Opart,
                                                      const float* __restrict__ ml,
                                                      float* __restrict__ out) {
    int r = blockIdx.x;
    int qtile = r >> 7, rl = r & 127;
    int d = threadIdx.x;
    float m[TSPLIT], l[TSPLIT];
    float M = -1e30f;
#pragma unroll
    for (int s = 0; s < TSPLIT; ++s) {
        const float* mlb = ml + (size_t)((qtile * TSPLIT + s) * QBLK + rl) * 2;
        m[s] = mlb[0];
        l[s] = mlb[1];
        M = fmaxf(M, m[s]);
    }
    float num = 0.f, den = 0.f;
#pragma unroll
    for (int s = 0; s < TSPLIT; ++s) {
        float w = __expf(m[s] - M);
        num += w * (float)Opart[((size_t)(qtile * TSPLIT + s) * QBLK + rl) * D_DIM + d];
        den += w * l[s];
    }
    out[(size_t)r * D_DIM + d] = num / den;
}

extern "C" void kernel_launch(void* const* d_in, const int* in_sizes, int n_in,
                              void* d_out, int out_size, void* d_ws, size_t ws_size,
                              hipStream_t stream) {
    const float* Q = (const float*)d_in[0];
    const float* K = (const float*)d_in[1];
    const float* V = (const float*)d_in[2];
    float* out = (float*)d_out;
    char* ws = (char*)d_ws;

    _Float16* Qh = (_Float16*)ws;                    // 4MB row-major
    _Float16* Kimg = (_Float16*)(ws + (4 << 20));    // 4MB tile-swizzled
    _Float16* Vimg = (_Float16*)(ws + (8 << 20));    // 4MB tile-swizzled transpose
    _Float16* Opart = (_Float16*)(ws + (12 << 20));  // 32MB f16 partials
    float* ml = (float*)(ws + (44 << 20));           // 512KB

    const int n4 = S_LEN * D_DIM / 4;       // 524288 float4s
    const int nchunks = S_LEN * D_DIM / 8;  // 262144 16B chunks
    cvt_kernel<<<n4 / 256, 256, 0, stream>>>(Q, Qh, n4);
    cvt_swz_kernel<<<nchunks / 256, 256, 0, stream>>>(K, Kimg, nchunks);
    dim3 tg(T_LEN / 64, D_DIM / 64);
    vt_swz_kernel<<<tg, 256, 0, stream>>>(V, Vimg);
    dim3 ag(NQT, TSPLIT);
    attn_kernel<<<ag, 512, 0, stream>>>(Qh, Kimg, Vimg, Opart, ml);
    combine_kernel<<<S_LEN, 256, 0, stream>>>(Opart, ml, out);
}

// Round 4
// 115.157 us; speedup vs baseline: 1.9786x; 1.9786x over previous
//
#include <hip/hip_runtime.h>
#include <hip/hip_fp16.h>

#define S_LEN 8192
#define T_LEN 8192
#define D_DIM 256
#define QBLK 256
#define KVBLK 32
#define TSPLIT 8
#define TCHUNK (T_LEN / TSPLIT)   // 1024
#define NKV (TCHUNK / KVBLK)      // 32 tiles per block
#define NQT (S_LEN / QBLK)        // 32
#define KTILE_BYTES 16384         // 32 keys x 256 d x 2B (swizzled image)
#define VTILE_BYTES 16384         // 256 d x 32 keys x 2B (swizzled image)
#define RESCALE_THR 4.0f

typedef _Float16 f16x8 __attribute__((ext_vector_type(8)));
typedef float f32x4 __attribute__((ext_vector_type(4)));

struct h4 { _Float16 h[4]; };

#define GLOAD_LDS16(g, l)                                              \
    __builtin_amdgcn_global_load_lds(                                  \
        (const __attribute__((address_space(1))) void*)(g),            \
        (__attribute__((address_space(3))) void*)(l), 16, 0, 0)

#define MFMA16(a, b, c) __builtin_amdgcn_mfma_f32_16x16x32_f16(a, b, c, 0, 0, 0)

// ---------------- Q: fp32 -> f16 row-major ----------------
__global__ __launch_bounds__(256) void cvt_kernel(const float* __restrict__ in,
                                                  _Float16* __restrict__ out, int n4) {
    int i = blockIdx.x * 256 + threadIdx.x;
    if (i < n4) {
        float4 v = ((const float4*)in)[i];
        h4 o;
        o.h[0] = (_Float16)v.x; o.h[1] = (_Float16)v.y;
        o.h[2] = (_Float16)v.z; o.h[3] = (_Float16)v.w;
        ((h4*)out)[i] = o;
    }
}

// ------- K -> Kimg: per-32-key tile [32 r][512B], granule swizzle ck^(r&7) -------
__global__ __launch_bounds__(256) void cvt_swz_kernel(const float* __restrict__ in,
                                                      _Float16* __restrict__ img,
                                                      int nchunks) {
    int id = blockIdx.x * 256 + threadIdx.x;
    if (id >= nchunks) return;
    int row = id >> 5, ck = id & 31;
    int t = row >> 5, r = row & 31;
    float4 a = *(const float4*)(in + (size_t)row * D_DIM + ck * 8);
    float4 b = *(const float4*)(in + (size_t)row * D_DIM + ck * 8 + 4);
    f16x8 o;
    o[0] = (_Float16)a.x; o[1] = (_Float16)a.y; o[2] = (_Float16)a.z; o[3] = (_Float16)a.w;
    o[4] = (_Float16)b.x; o[5] = (_Float16)b.y; o[6] = (_Float16)b.z; o[7] = (_Float16)b.w;
    *(f16x8*)((char*)img + (size_t)t * KTILE_BYTES + r * 512 + ((ck ^ (r & 7)) << 4)) = o;
}

// ------- V -> Vimg: per-32-key tile [256 d][64B], granule gk holds keys 8gk..8gk+7,
//         granule swizzle gk^(d&3) -------
__global__ __launch_bounds__(256) void vt_swz_kernel(const float* __restrict__ V,
                                                     _Float16* __restrict__ Vimg) {
    __shared__ float tile[32][260];
    const int t = blockIdx.x;  // one 32-key tile per block
#pragma unroll
    for (int i = 0; i < 8; ++i) {
        int idx = i * 256 + threadIdx.x;  // 2048 float4s = 32 keys x 64
        int kr = idx >> 6, c4 = idx & 63;
        float4 v = *(const float4*)(V + ((size_t)t * 32 + kr) * D_DIM + c4 * 4);
        tile[kr][c4 * 4 + 0] = v.x;
        tile[kr][c4 * 4 + 1] = v.y;
        tile[kr][c4 * 4 + 2] = v.z;
        tile[kr][c4 * 4 + 3] = v.w;
    }
    __syncthreads();
#pragma unroll
    for (int i = 0; i < 4; ++i) {
        int gid = i * 256 + threadIdx.x;  // 1024 granules = 256 d x 4 gk
        int d = gid >> 2, gk = gid & 3;
        f16x8 o;
#pragma unroll
        for (int j = 0; j < 8; ++j) o[j] = (_Float16)tile[gk * 8 + j][d];
        *(f16x8*)((char*)Vimg + (size_t)t * VTILE_BYTES + d * 64 +
                  ((gk ^ (d & 3)) << 4)) = o;
    }
}

// ---------------- flash attention ----------------
// 8 waves x 32 q-rows (M_rep=2). Swapped QK^T (A=K,B=Q) -> in-register P via
// cvt_pkrtz + shfl. Double-buffered K/V tiles, raw s_barrier + counted vmcnt.
__global__ __launch_bounds__(512, 2) void attn_kernel(
    const _Float16* __restrict__ Qh, const _Float16* __restrict__ Kimg,
    const _Float16* __restrict__ Vimg, _Float16* __restrict__ Opart,
    float* __restrict__ ml) {
    __shared__ __align__(16) char smem[65536];  // sK[2]@0,16K ; sV[2]@32K,48K
    const int tid = threadIdx.x;
    const int wave = tid >> 6, lane = tid & 63;
    const int g = lane >> 4, c = lane & 15;
    const int qtile = blockIdx.x, split = blockIdx.y;
    const int tile0 = split * NKV;

    // ---- Q B-fragments: B[n=q=lane&15][k = ks*32 + g*8 + j] ----
    f16x8 qf[2][8];
    {
        const size_t qrow0 = (size_t)qtile * QBLK + wave * 32 + c;
#pragma unroll
        for (int mi = 0; mi < 2; ++mi)
#pragma unroll
            for (int ks = 0; ks < 8; ++ks)
                qf[mi][ks] =
                    *(const f16x8*)(Qh + (qrow0 + mi * 16) * D_DIM + (ks * 4 + g) * 8);
    }

    f32x4 acc[2][16];
#pragma unroll
    for (int mi = 0; mi < 2; ++mi)
#pragma unroll
        for (int dt = 0; dt < 16; ++dt) acc[mi][dt] = (f32x4){0.f, 0.f, 0.f, 0.f};
    float m[2] = {-1e30f, -1e30f}, l[2] = {0.f, 0.f};

    const int stg_l = wave * 1024;        // wave-uniform LDS base per 8KB round
    const int stg_g = stg_l + lane * 16;  // per-lane global offset

    // ---- prologue: stage tile0 into buffer 0 ----
    {
        const char* Kt = (const char*)Kimg + (size_t)tile0 * KTILE_BYTES;
        const char* Vt = (const char*)Vimg + (size_t)tile0 * VTILE_BYTES;
#pragma unroll
        for (int i = 0; i < 2; ++i) {
            GLOAD_LDS16(Kt + i * 8192 + stg_g, smem + i * 8192 + stg_l);
            GLOAD_LDS16(Vt + i * 8192 + stg_g, smem + 32768 + i * 8192 + stg_l);
        }
    }

    for (int kt = 0; kt < NKV; ++kt) {
        const int cur = kt & 1;
        if (kt + 1 < NKV) {
            const char* Kt = (const char*)Kimg + (size_t)(tile0 + kt + 1) * KTILE_BYTES;
            const char* Vt = (const char*)Vimg + (size_t)(tile0 + kt + 1) * VTILE_BYTES;
            const int nb = (cur ^ 1) * 16384;
#pragma unroll
            for (int i = 0; i < 2; ++i) {
                GLOAD_LDS16(Kt + i * 8192 + stg_g, smem + nb + i * 8192 + stg_l);
                GLOAD_LDS16(Vt + i * 8192 + stg_g, smem + 32768 + nb + i * 8192 + stg_l);
            }
            asm volatile("s_waitcnt vmcnt(4)" ::: "memory");  // cur's 4 landed; next's in flight
        } else {
            asm volatile("s_waitcnt vmcnt(0)" ::: "memory");
        }
        __builtin_amdgcn_s_barrier();

        const char* sK = smem + cur * 16384;
        const char* sV = smem + 32768 + cur * 16384;

        // ---- QK^T swapped: st[mi][ct] = S^T[key=ct*16+g*4+r][q=mi*16+c] ----
        f32x4 st[2][2];
#pragma unroll
        for (int mi = 0; mi < 2; ++mi)
#pragma unroll
            for (int ct = 0; ct < 2; ++ct) st[mi][ct] = (f32x4){0.f, 0.f, 0.f, 0.f};
        __builtin_amdgcn_s_setprio(1);
#pragma unroll
        for (int ks = 0; ks < 8; ++ks) {
            const int ck = ((ks * 4 + g) ^ (c & 7)) << 4;
            f16x8 kf0 = *(const f16x8*)(sK + c * 512 + ck);
            f16x8 kf1 = *(const f16x8*)(sK + 8192 + c * 512 + ck);
            st[0][0] = MFMA16(kf0, qf[0][ks], st[0][0]);
            st[0][1] = MFMA16(kf1, qf[0][ks], st[0][1]);
            st[1][0] = MFMA16(kf0, qf[1][ks], st[1][0]);
            st[1][1] = MFMA16(kf1, qf[1][ks], st[1][1]);
        }
        __builtin_amdgcn_s_setprio(0);

        // ---- online softmax (row q = c per mi; keys spread over g,ct,r) ----
        unsigned int pk[2][2][2];  // [mi][ct][pair]
#pragma unroll
        for (int mi = 0; mi < 2; ++mi) {
            float pm = st[mi][0][0];
#pragma unroll
            for (int ct = 0; ct < 2; ++ct)
#pragma unroll
                for (int r = 0; r < 4; ++r) pm = fmaxf(pm, st[mi][ct][r]);
            pm = fmaxf(pm, __shfl_xor(pm, 16));
            pm = fmaxf(pm, __shfl_xor(pm, 32));
            if (__any(pm > m[mi] + RESCALE_THR)) {
                float mn = fmaxf(m[mi], pm);
                float sc = __expf(m[mi] - mn);
                m[mi] = mn;
                l[mi] *= sc;
                float fr[4];
#pragma unroll
                for (int r = 0; r < 4; ++r) fr[r] = __shfl(sc, (g << 4) | (g * 4 + r));
#pragma unroll
                for (int dt = 0; dt < 16; ++dt)
#pragma unroll
                    for (int r = 0; r < 4; ++r) acc[mi][dt][r] *= fr[r];
            }
            float rs = 0.f;
#pragma unroll
            for (int ct = 0; ct < 2; ++ct)
#pragma unroll
                for (int r = 0; r < 4; ++r) {
                    float p = __expf(st[mi][ct][r] - m[mi]);
                    st[mi][ct][r] = p;
                    rs += p;
                }
            rs += __shfl_xor(rs, 16);
            rs += __shfl_xor(rs, 32);
            l[mi] += rs;
#pragma unroll
            for (int ct = 0; ct < 2; ++ct) {
                pk[mi][ct][0] = __builtin_bit_cast(
                    unsigned int,
                    __builtin_amdgcn_cvt_pkrtz(st[mi][ct][0], st[mi][ct][1]));
                pk[mi][ct][1] = __builtin_bit_cast(
                    unsigned int,
                    __builtin_amdgcn_cvt_pkrtz(st[mi][ct][2], st[mi][ct][3]));
            }
        }

        // ---- redistribute P -> PV A-frags: lane needs P[q=c][keys g*8..g*8+7] ----
        union PU { unsigned int u[4]; f16x8 v; };
        PU pu[2];
#pragma unroll
        for (int mi = 0; mi < 2; ++mi)
#pragma unroll
            for (int w = 0; w < 4; ++w) {
                int src = ((((g & 1) << 1) + (w >> 1)) << 4) | c;
                int t0 = __shfl((int)pk[mi][0][w & 1], src);
                int t1 = __shfl((int)pk[mi][1][w & 1], src);
                pu[mi].u[w] = (unsigned int)((g >> 1) ? t1 : t0);
            }

        // ---- PV: acc[mi][dt] += P * V ----
        __builtin_amdgcn_s_setprio(1);
#pragma unroll
        for (int dt = 0; dt < 16; ++dt) {
            f16x8 vf = *(const f16x8*)(sV + (dt * 16 + c) * 64 + ((g ^ (c & 3)) << 4));
            acc[0][dt] = MFMA16(pu[0].v, vf, acc[0][dt]);
            acc[1][dt] = MFMA16(pu[1].v, vf, acc[1][dt]);
        }
        __builtin_amdgcn_s_setprio(0);

        __builtin_amdgcn_s_barrier();  // all reads of cur done before next stage overwrites
    }

    // ---- epilogue: unnormalized partial O (f16) + (m,l) ----
    _Float16* Ob = Opart + (size_t)(qtile * TSPLIT + split) * QBLK * D_DIM;
#pragma unroll
    for (int mi = 0; mi < 2; ++mi)
#pragma unroll
        for (int dt = 0; dt < 16; ++dt)
#pragma unroll
            for (int r = 0; r < 4; ++r) {
                int row = wave * 32 + mi * 16 + g * 4 + r;
                int col = dt * 16 + c;
                Ob[(size_t)row * D_DIM + col] = (_Float16)acc[mi][dt][r];
            }
    if (g == 0) {
        float* mlb = ml + (size_t)((qtile * TSPLIT + split) * QBLK) * 2;
#pragma unroll
        for (int mi = 0; mi < 2; ++mi) {
            int row = wave * 32 + mi * 16 + c;
            mlb[row * 2 + 0] = m[mi];
            mlb[row * 2 + 1] = l[mi];
        }
    }
}

// ---------------- combine TSPLIT partials ----------------
__global__ __launch_bounds__(256) void combine_kernel(const _Float16* __restrict__ Opart,
                                                      const float* __restrict__ ml,
                                                      float* __restrict__ out) {
    int r = blockIdx.x;
    int qtile = r >> 8, rl = r & 255;
    int d = threadIdx.x;
    float mv[TSPLIT], lv[TSPLIT];
    float M = -1e30f;
#pragma unroll
    for (int s = 0; s < TSPLIT; ++s) {
        const float* mlb = ml + (size_t)((qtile * TSPLIT + s) * QBLK + rl) * 2;
        mv[s] = mlb[0];
        lv[s] = mlb[1];
        M = fmaxf(M, mv[s]);
    }
    float num = 0.f, den = 0.f;
#pragma unroll
    for (int s = 0; s < TSPLIT; ++s) {
        float w = __expf(mv[s] - M);
        num += w * (float)Opart[((size_t)(qtile * TSPLIT + s) * QBLK + rl) * D_DIM + d];
        den += w * lv[s];
    }
    out[(size_t)r * D_DIM + d] = num / den;
}

extern "C" void kernel_launch(void* const* d_in, const int* in_sizes, int n_in,
                              void* d_out, int out_size, void* d_ws, size_t ws_size,
                              hipStream_t stream) {
    const float* Q = (const float*)d_in[0];
    const float* K = (const float*)d_in[1];
    const float* V = (const float*)d_in[2];
    float* out = (float*)d_out;
    char* ws = (char*)d_ws;

    _Float16* Qh = (_Float16*)ws;                    // 4MB row-major f16
    _Float16* Kimg = (_Float16*)(ws + (4 << 20));    // 4MB swizzled 32-key tiles
    _Float16* Vimg = (_Float16*)(ws + (8 << 20));    // 4MB swizzled transposed tiles
    _Float16* Opart = (_Float16*)(ws + (12 << 20));  // 32MB f16 partials
    float* ml = (float*)(ws + (44 << 20));           // 512KB

    const int n4 = S_LEN * D_DIM / 4;
    const int nchunks = S_LEN * D_DIM / 8;  // 262144
    cvt_kernel<<<n4 / 256, 256, 0, stream>>>(Q, Qh, n4);
    cvt_swz_kernel<<<nchunks / 256, 256, 0, stream>>>(K, Kimg, nchunks);
    vt_swz_kernel<<<T_LEN / 32, 256, 0, stream>>>(V, Vimg);
    dim3 ag(NQT, TSPLIT);
    attn_kernel<<<ag, 512, 0, stream>>>(Qh, Kimg, Vimg, Opart, ml);
    combine_kernel<<<S_LEN, 256, 0, stream>>>(Opart, ml, out);
}

// Round 5
// 110.704 us; speedup vs baseline: 2.0581x; 1.0402x over previous
//
#include <hip/hip_runtime.h>
#include <hip/hip_fp16.h>

#define S_LEN 8192
#define T_LEN 8192
#define D_DIM 256
#define QBLK 128
#define KVBLK 32
#define TSPLIT 8
#define TCHUNK (T_LEN / TSPLIT)   // 1024
#define NKV (TCHUNK / KVBLK)      // 32 tiles per block
#define NQT (S_LEN / QBLK)        // 64
#define KTILE_BYTES 16384         // 32 keys x 256 d x 2B (swizzled image)
#define VTILE_BYTES 16384         // 256 d x 32 keys x 2B (swizzled, pi-permuted image)
#define RESCALE_THR 6.0f          // log2 domain (~= e^4.16)
#define LOG2E 1.44269504f

typedef _Float16 f16x8 __attribute__((ext_vector_type(8)));
typedef float f32x4 __attribute__((ext_vector_type(4)));

struct h4 { _Float16 h[4]; };

#define GLOAD_LDS16(g, l)                                              \
    __builtin_amdgcn_global_load_lds(                                  \
        (const __attribute__((address_space(1))) void*)(g),            \
        (__attribute__((address_space(3))) void*)(l), 16, 0, 0)

#define MFMA16(a, b, c) __builtin_amdgcn_mfma_f32_16x16x32_f16(a, b, c, 0, 0, 0)

// ---------------- Q: fp32 -> f16 row-major, pre-scaled by log2(e) ----------------
__global__ __launch_bounds__(256) void cvt_kernel(const float* __restrict__ in,
                                                  _Float16* __restrict__ out, int n4) {
    int i = blockIdx.x * 256 + threadIdx.x;
    if (i < n4) {
        float4 v = ((const float4*)in)[i];
        h4 o;
        o.h[0] = (_Float16)(v.x * LOG2E); o.h[1] = (_Float16)(v.y * LOG2E);
        o.h[2] = (_Float16)(v.z * LOG2E); o.h[3] = (_Float16)(v.w * LOG2E);
        ((h4*)out)[i] = o;
    }
}

// ------- K -> Kimg: per-32-key tile [32 r][512B], granule swizzle ck^(r&7) -------
__global__ __launch_bounds__(256) void cvt_swz_kernel(const float* __restrict__ in,
                                                      _Float16* __restrict__ img,
                                                      int nchunks) {
    int id = blockIdx.x * 256 + threadIdx.x;
    if (id >= nchunks) return;
    int row = id >> 5, ck = id & 31;
    int t = row >> 5, r = row & 31;
    float4 a = *(const float4*)(in + (size_t)row * D_DIM + ck * 8);
    float4 b = *(const float4*)(in + (size_t)row * D_DIM + ck * 8 + 4);
    f16x8 o;
    o[0] = (_Float16)a.x; o[1] = (_Float16)a.y; o[2] = (_Float16)a.z; o[3] = (_Float16)a.w;
    o[4] = (_Float16)b.x; o[5] = (_Float16)b.y; o[6] = (_Float16)b.z; o[7] = (_Float16)b.w;
    *(f16x8*)((char*)img + (size_t)t * KTILE_BYTES + r * 512 + ((ck ^ (r & 7)) << 4)) = o;
}

// ------- V -> Vimg: per-32-key tile [256 d][64B].
// Granule gk elem j holds key pi(gk*8+j) = (j>>2)*16 + gk*4 + (j&3)  (k-axis permute,
// matched by the P-fragment packing in the attn kernel).
// Granule position swizzled: gk ^ ((d>>1)&3)  -> conflict-free b128 reads. -------
__global__ __launch_bounds__(256) void vt_swz_kernel(const float* __restrict__ V,
                                                     _Float16* __restrict__ Vimg) {
    __shared__ float tile[32][260];
    const int t = blockIdx.x;  // one 32-key tile per block
#pragma unroll
    for (int i = 0; i < 8; ++i) {
        int idx = i * 256 + threadIdx.x;  // 2048 float4s = 32 keys x 64
        int kr = idx >> 6, c4 = idx & 63;
        float4 v = *(const float4*)(V + ((size_t)t * 32 + kr) * D_DIM + c4 * 4);
        tile[kr][c4 * 4 + 0] = v.x;
        tile[kr][c4 * 4 + 1] = v.y;
        tile[kr][c4 * 4 + 2] = v.z;
        tile[kr][c4 * 4 + 3] = v.w;
    }
    __syncthreads();
#pragma unroll
    for (int i = 0; i < 4; ++i) {
        int gid = i * 256 + threadIdx.x;  // 1024 granules = 256 d x 4 gk
        int d = gid >> 2, gk = gid & 3;
        f16x8 o;
#pragma unroll
        for (int j = 0; j < 8; ++j)
            o[j] = (_Float16)tile[(j >> 2) * 16 + gk * 4 + (j & 3)][d];
        *(f16x8*)((char*)Vimg + (size_t)t * VTILE_BYTES + d * 64 +
                  ((gk ^ ((d >> 1) & 3)) << 4)) = o;
    }
}

// ---------------- flash attention ----------------
// 4 waves x 32 q-rows (M_rep=2); grid 64x8 = 512 blocks = 2 independent blocks/CU.
// Swapped QK^T (A=K,B=Q) -> P packed in-lane via cvt_pkrtz (pi-permuted V absorbs
// the k-order). Double-buffered K/V tiles, raw s_barrier + counted vmcnt(8).
__global__ __launch_bounds__(256, 2) void attn_kernel(
    const _Float16* __restrict__ Qh, const _Float16* __restrict__ Kimg,
    const _Float16* __restrict__ Vimg, _Float16* __restrict__ Opart,
    float* __restrict__ ml) {
    __shared__ __align__(16) char smem[65536];  // sK[2]@0,16K ; sV[2]@32K,48K
    const int tid = threadIdx.x;
    const int wave = tid >> 6, lane = tid & 63;
    const int g = lane >> 4, c = lane & 15;
    const int qtile = blockIdx.x, split = blockIdx.y;
    const int tile0 = split * NKV;

    // ---- Q B-fragments: B[n=q=c][k = ks*32 + g*8 + j] ----
    f16x8 qf[2][8];
    {
        const size_t qrow0 = (size_t)qtile * QBLK + wave * 32 + c;
#pragma unroll
        for (int mi = 0; mi < 2; ++mi)
#pragma unroll
            for (int ks = 0; ks < 8; ++ks)
                qf[mi][ks] =
                    *(const f16x8*)(Qh + (qrow0 + mi * 16) * D_DIM + (ks * 4 + g) * 8);
    }
    asm volatile("s_waitcnt vmcnt(0)" ::: "memory");  // keep Q loads out of the pipeline count

    f32x4 acc[2][16];
#pragma unroll
    for (int mi = 0; mi < 2; ++mi)
#pragma unroll
        for (int dt = 0; dt < 16; ++dt) acc[mi][dt] = (f32x4){0.f, 0.f, 0.f, 0.f};
    float m[2] = {-1e30f, -1e30f}, l[2] = {0.f, 0.f};

    const int othr = tid * 16;  // 256 threads x 16B = 4KB per round

    // ---- prologue: stage tile0 into buffer 0 (8 loads in flight) ----
    {
        const char* Kt = (const char*)Kimg + (size_t)tile0 * KTILE_BYTES;
        const char* Vt = (const char*)Vimg + (size_t)tile0 * VTILE_BYTES;
#pragma unroll
        for (int i = 0; i < 4; ++i) {
            GLOAD_LDS16(Kt + i * 4096 + othr, smem + i * 4096 + othr);
            GLOAD_LDS16(Vt + i * 4096 + othr, smem + 32768 + i * 4096 + othr);
        }
    }

    for (int kt = 0; kt < NKV; ++kt) {
        const int cur = kt & 1;
        if (kt + 1 < NKV) {
            const char* Kt = (const char*)Kimg + (size_t)(tile0 + kt + 1) * KTILE_BYTES;
            const char* Vt = (const char*)Vimg + (size_t)(tile0 + kt + 1) * VTILE_BYTES;
            const int nb = (cur ^ 1) * 16384;
#pragma unroll
            for (int i = 0; i < 4; ++i) {
                GLOAD_LDS16(Kt + i * 4096 + othr, smem + nb + i * 4096 + othr);
                GLOAD_LDS16(Vt + i * 4096 + othr, smem + 32768 + nb + i * 4096 + othr);
            }
            asm volatile("s_waitcnt vmcnt(8)" ::: "memory");  // current tile landed; next in flight
        } else {
            asm volatile("s_waitcnt vmcnt(0)" ::: "memory");
        }
        __builtin_amdgcn_s_barrier();

        const char* sK = smem + cur * 16384;
        const char* sV = smem + 32768 + cur * 16384;

        // ---- QK^T swapped: st[mi][ct] = S^T[key=ct*16+g*4+r][q=mi*16+c] ----
        f32x4 st[2][2];
#pragma unroll
        for (int mi = 0; mi < 2; ++mi)
#pragma unroll
            for (int ct = 0; ct < 2; ++ct) st[mi][ct] = (f32x4){0.f, 0.f, 0.f, 0.f};
        __builtin_amdgcn_s_setprio(1);
#pragma unroll
        for (int ks = 0; ks < 8; ++ks) {
            const int ck = ((ks * 4 + g) ^ (c & 7)) << 4;
            f16x8 kf0 = *(const f16x8*)(sK + c * 512 + ck);
            f16x8 kf1 = *(const f16x8*)(sK + 8192 + c * 512 + ck);
            st[0][0] = MFMA16(kf0, qf[0][ks], st[0][0]);
            st[0][1] = MFMA16(kf1, qf[0][ks], st[0][1]);
            st[1][0] = MFMA16(kf0, qf[1][ks], st[1][0]);
            st[1][1] = MFMA16(kf1, qf[1][ks], st[1][1]);
        }
        __builtin_amdgcn_s_setprio(0);

        // ---- online softmax, base-2 (row q = c; keys spread over g,ct,r) ----
        union PU { unsigned int u[4]; f16x8 v; };
        PU pu[2];
#pragma unroll
        for (int mi = 0; mi < 2; ++mi) {
            float pm = st[mi][0][0];
#pragma unroll
            for (int ct = 0; ct < 2; ++ct)
#pragma unroll
                for (int r = 0; r < 4; ++r) pm = fmaxf(pm, st[mi][ct][r]);
            pm = fmaxf(pm, __shfl_xor(pm, 16));
            pm = fmaxf(pm, __shfl_xor(pm, 32));
            if (__any(pm > m[mi] + RESCALE_THR)) {
                float mn = fmaxf(m[mi], pm);
                float sc = exp2f(m[mi] - mn);
                m[mi] = mn;
                l[mi] *= sc;
                float fr[4];
#pragma unroll
                for (int r = 0; r < 4; ++r) fr[r] = __shfl(sc, (g << 4) | (g * 4 + r));
#pragma unroll
                for (int dt = 0; dt < 16; ++dt)
#pragma unroll
                    for (int r = 0; r < 4; ++r) acc[mi][dt][r] *= fr[r];
            }
            float rs = 0.f;
#pragma unroll
            for (int ct = 0; ct < 2; ++ct)
#pragma unroll
                for (int r = 0; r < 4; ++r) {
                    float p = exp2f(st[mi][ct][r] - m[mi]);
                    st[mi][ct][r] = p;
                    rs += p;
                }
            rs += __shfl_xor(rs, 16);
            rs += __shfl_xor(rs, 32);
            l[mi] += rs;
            // pack P in-lane: A'[q=c][kslot g*8+j] with pi(g*8+j)=(j>>2)*16+g*4+(j&3)
            pu[mi].u[0] = __builtin_bit_cast(
                unsigned int, __builtin_amdgcn_cvt_pkrtz(st[mi][0][0], st[mi][0][1]));
            pu[mi].u[1] = __builtin_bit_cast(
                unsigned int, __builtin_amdgcn_cvt_pkrtz(st[mi][0][2], st[mi][0][3]));
            pu[mi].u[2] = __builtin_bit_cast(
                unsigned int, __builtin_amdgcn_cvt_pkrtz(st[mi][1][0], st[mi][1][1]));
            pu[mi].u[3] = __builtin_bit_cast(
                unsigned int, __builtin_amdgcn_cvt_pkrtz(st[mi][1][2], st[mi][1][3]));
        }

        // ---- PV: acc[mi][dt] += P' * V'  (pi-permuted k-axis on both sides) ----
        __builtin_amdgcn_s_setprio(1);
#pragma unroll
        for (int dt = 0; dt < 16; ++dt) {
            const int d = dt * 16 + c;
            f16x8 vf = *(const f16x8*)(sV + d * 64 + ((g ^ ((c >> 1) & 3)) << 4));
            acc[0][dt] = MFMA16(pu[0].v, vf, acc[0][dt]);
            acc[1][dt] = MFMA16(pu[1].v, vf, acc[1][dt]);
        }
        __builtin_amdgcn_s_setprio(0);

        __builtin_amdgcn_s_barrier();  // all reads of cur done before next stage overwrites
    }

    // ---- epilogue: unnormalized partial O (f16) + (m,l) ----
    _Float16* Ob = Opart + (size_t)(qtile * TSPLIT + split) * QBLK * D_DIM;
#pragma unroll
    for (int mi = 0; mi < 2; ++mi)
#pragma unroll
        for (int dt = 0; dt < 16; ++dt)
#pragma unroll
            for (int r = 0; r < 4; ++r) {
                int row = wave * 32 + mi * 16 + g * 4 + r;
                int col = dt * 16 + c;
                Ob[(size_t)row * D_DIM + col] = (_Float16)acc[mi][dt][r];
            }
    if (g == 0) {
        float* mlb = ml + (size_t)((qtile * TSPLIT + split) * QBLK) * 2;
#pragma unroll
        for (int mi = 0; mi < 2; ++mi) {
            int row = wave * 32 + mi * 16 + c;
            mlb[row * 2 + 0] = m[mi];
            mlb[row * 2 + 1] = l[mi];
        }
    }
}

// ---------------- combine TSPLIT partials (base-2 stats) ----------------
__global__ __launch_bounds__(256) void combine_kernel(const _Float16* __restrict__ Opart,
                                                      const float* __restrict__ ml,
                                                      float* __restrict__ out) {
    int r = blockIdx.x;
    int qtile = r >> 7, rl = r & 127;
    int d = threadIdx.x;
    float mv[TSPLIT], lv[TSPLIT];
    float M = -1e30f;
#pragma unroll
    for (int s = 0; s < TSPLIT; ++s) {
        const float* mlb = ml + (size_t)((qtile * TSPLIT + s) * QBLK + rl) * 2;
        mv[s] = mlb[0];
        lv[s] = mlb[1];
        M = fmaxf(M, mv[s]);
    }
    float num = 0.f, den = 0.f;
#pragma unroll
    for (int s = 0; s < TSPLIT; ++s) {
        float w = exp2f(mv[s] - M);
        num += w * (float)Opart[((size_t)(qtile * TSPLIT + s) * QBLK + rl) * D_DIM + d];
        den += w * lv[s];
    }
    out[(size_t)r * D_DIM + d] = num / den;
}

extern "C" void kernel_launch(void* const* d_in, const int* in_sizes, int n_in,
                              void* d_out, int out_size, void* d_ws, size_t ws_size,
                              hipStream_t stream) {
    const float* Q = (const float*)d_in[0];
    const float* K = (const float*)d_in[1];
    const float* V = (const float*)d_in[2];
    float* out = (float*)d_out;
    char* ws = (char*)d_ws;

    _Float16* Qh = (_Float16*)ws;                    // 4MB row-major f16 (x log2e)
    _Float16* Kimg = (_Float16*)(ws + (4 << 20));    // 4MB swizzled 32-key tiles
    _Float16* Vimg = (_Float16*)(ws + (8 << 20));    // 4MB swizzled pi-permuted tiles
    _Float16* Opart = (_Float16*)(ws + (12 << 20));  // 32MB f16 partials
    float* ml = (float*)(ws + (44 << 20));           // 512KB

    const int n4 = S_LEN * D_DIM / 4;
    const int nchunks = S_LEN * D_DIM / 8;  // 262144
    cvt_kernel<<<n4 / 256, 256, 0, stream>>>(Q, Qh, n4);
    cvt_swz_kernel<<<nchunks / 256, 256, 0, stream>>>(K, Kimg, nchunks);
    vt_swz_kernel<<<T_LEN / 32, 256, 0, stream>>>(V, Vimg);
    dim3 ag(NQT, TSPLIT);
    attn_kernel<<<ag, 256, 0, stream>>>(Qh, Kimg, Vimg, Opart, ml);
    combine_kernel<<<S_LEN, 256, 0, stream>>>(Opart, ml, out);
}